// Round 5
// baseline (833.592 us; speedup 1.0000x reference)
//
#include <hip/hip_runtime.h>
#include <math.h>

// VectorQuantizer on MI355X — round 5: bf16-split MFMA scorer (ws-layout fix).
// latents [64,256,32,32] f32, embedding [1024,256] f32.
// Outputs (concat fp32): quant_st [16777216], loss [1], indices-as-float [65536].
//
// VALIDATED (round 2/3, absmax 0): numpy index semantics are
//   dist = fl32( fl32(Sx + Ek) - fl32(2*dot) ), argmin first-index ties,
// Sx/Ek = numpy pairwise fp32 (two 128-blocks, 8 accumulators, binary tree),
// dot = sequential ascending-c fp32 FMA chain.
//
// ROUND-4 BUG (root cause of the abort): WS_WL overlapped the selIdx region by
// 6144 B -> flagged pixels could lose their worklist slot -> selIdx left as
// 0xAA poison -> k_gather wild gather -> GPU page fault. WS_WL now 794624.
//
// Architecture:
//  k_prep    : Ek[k] = numpy-pairwise fp32 sum(e_k^2); zero loss + worklist count
//  k_embconv : emb_hi = bf16(emb)
//  k_score   : MFMA engine. x split hi/lo (bf16), dot ~= x_hi.e_hi + x_lo.e_hi
//              (error sigma ~3e-5 on a gap << MARGIN_S). Per-pixel top-2; gap >=
//              margin -> engine top-1 IS the quantized argmin; else -> worklist.
//  k_refine  : block per flagged pixel; exact fp32-chain re-scan of all 1024
//              codes with validated numpy semantics (incl. pairwise Sx).
//  k_gather  : gather + straight-through write + fp64 loss partials
//  k_loss    : loss = 1.25 * total / 16777216

#define DIM 256
#define BSTRIDE 262144
#define OUT_LOSS 16777216
#define OUT_IDX  16777217
#define MARGIN_S 3e-4f

// ws byte offsets (total 1056768 B; proven to fit in rounds 1-2)
#define WS_LOSS  0
#define WS_COUNT 8
#define WS_ENORM 64
#define WS_EMBH  8192
#define WS_SEL   532480      // 8192 + 1024*256*2
#define WS_WL    794624      // 532480 + 65536*4  (round-4 bug: was 788480)

typedef __attribute__((ext_vector_type(8))) short short8;
typedef __attribute__((ext_vector_type(4))) float f32x4;

__device__ inline unsigned short f2bf(float f) {   // RNE f32 -> bf16 bits
  unsigned u = __float_as_uint(f);
  unsigned r = 0x7FFFu + ((u >> 16) & 1u);
  return (unsigned short)((u + r) >> 16);
}
__device__ inline float bf2f(unsigned short h) {
  return __uint_as_float(((unsigned)h) << 16);
}

// ---------------- k_prep: numpy-pairwise |e_k|^2, zero loss/count -----------
__global__ void k_prep(const float* __restrict__ emb, float* __restrict__ enormQ,
                       double* __restrict__ lossAcc, int* __restrict__ count) {
  const int k = blockIdx.x * 64 + threadIdx.x;   // 16 blocks x 64
  if (blockIdx.x == 0 && threadIdx.x == 0) { *lossAcc = 0.0; *count = 0; }
  if (k >= 1024) return;
  const float* e = emb + (size_t)k * DIM;
  float blk[2];
  #pragma unroll
  for (int h = 0; h < 2; ++h) {
    const float* a = e + h * 128;
    float r[8];
    #pragma unroll
    for (int j = 0; j < 8; ++j) r[j] = __fmul_rn(a[j], a[j]);
    for (int i = 8; i < 128; i += 8)
      #pragma unroll
      for (int j = 0; j < 8; ++j) r[j] = __fadd_rn(r[j], __fmul_rn(a[i+j], a[i+j]));
    blk[h] = __fadd_rn(__fadd_rn(__fadd_rn(r[0], r[1]), __fadd_rn(r[2], r[3])),
                       __fadd_rn(__fadd_rn(r[4], r[5]), __fadd_rn(r[6], r[7])));
  }
  enormQ[k] = __fadd_rn(blk[0], blk[1]);
}

// ---------------- k_embconv: emb -> bf16 hi ---------------------------------
__global__ void k_embconv(const float* __restrict__ emb, unsigned short* __restrict__ embHi) {
  const int i = (blockIdx.x * 256 + threadIdx.x) * 4;   // 256 blocks x 256
  float4 v = *(const float4*)(emb + i);
  unsigned r0 = (unsigned)f2bf(v.x) | ((unsigned)f2bf(v.y) << 16);
  unsigned r1 = (unsigned)f2bf(v.z) | ((unsigned)f2bf(v.w) << 16);
  uint2 st; st.x = r0; st.y = r1;
  *(uint2*)(embHi + i) = st;
}

// ---------------- k_score: MFMA engine + top-2 filter -----------------------
// 1024 blocks x 256 threads (4 waves). Block = 64 pixels; wave = 16 pixels.
// A (16 pix x 256 feats, hi+lo bf16) register-resident: 64 VGPRs.
// B (16 codes x 256 feats bf16) double-buffered in LDS per chunk; 64 chunks.
// MFMA 16x16x32: A[m=lane&15][k=quad*8+j], B[n=lane&15][k=quad*8+j],
//                D[m=quad*4+reg][n=lane&15]  (guide §3, m89/m91 verified).
__launch_bounds__(256, 2)
__global__ void k_score(const float* __restrict__ lat,
                        const unsigned short* __restrict__ embHi,
                        const float* __restrict__ enormQ,
                        int* __restrict__ selIdx, float* __restrict__ out,
                        int* __restrict__ count, int* __restrict__ worklist) {
  __shared__ __align__(16) unsigned short sB[2 * 16 * 264];  // 16.5 KB (+8/row pad)
  __shared__ float sNorm[1024];                              // 4 KB

  const int t = threadIdx.x;
  const int w = t >> 6;          // wave 0..3
  const int L = t & 63;          // lane
  const int lane15 = L & 15;
  const int quad = L >> 4;

  const int pix0 = blockIdx.x * 64;
  const int bImg = pix0 >> 10;
  const int hw0 = pix0 & 1023;

  // stage norms to LDS
  for (int i = t; i < 1024; i += 256) sNorm[i] = enormQ[i];

  // ---- A fragments: 16 pixels of this wave, all 8 k-steps, hi+lo ----
  const int myPixHw = hw0 + w * 16 + lane15;
  const float* latPix = lat + (size_t)bImg * BSTRIDE + myPixHw;
  short8 aHi[8], aLo[8];
  #pragma unroll
  for (int ks = 0; ks < 8; ++ks) {
    #pragma unroll
    for (int j = 0; j < 8; ++j) {
      float f = latPix[(size_t)(ks * 32 + quad * 8 + j) * 1024];
      unsigned short hb = f2bf(f);
      unsigned short lb = f2bf(f - bf2f(hb));
      aHi[ks][j] = (short)hb;
      aLo[ks][j] = (short)lb;
    }
  }

  // ---- per-lane top-2 state (4 pixel-slots r=0..3: pixel quad*4+r) ----
  float b1[4], b2[4];
  int i1[4], i2[4];
  #pragma unroll
  for (int r = 0; r < 4; ++r) { b1[r] = INFINITY; b2[r] = INFINITY; i1[r] = 0x7fffffff; i2[r] = 0x7fffffff; }

  // ---- B staging helpers: thread t stages 2x16B per chunk ----
  const int s0 = t, s1 = 256 + t;
  const int n0 = s0 >> 5, o0 = s0 & 31;   // code row, 16B-chunk within row
  const int n1 = s1 >> 5, o1 = s1 & 31;

  // prologue: stage chunk 0
  {
    short8 p0 = *(const short8*)(embHi + ((size_t)(0 * 16 + n0) * 256 + o0 * 8));
    short8 p1 = *(const short8*)(embHi + ((size_t)(0 * 16 + n1) * 256 + o1 * 8));
    *(short8*)(sB + n0 * 264 + o0 * 8) = p0;
    *(short8*)(sB + n1 * 264 + o1 * 8) = p1;
  }
  __syncthreads();

  for (int ch = 0; ch < 64; ++ch) {
    const int cur = ch & 1;
    short8 p0, p1;
    if (ch < 63) {   // prefetch next chunk into regs (overlaps MFMA)
      p0 = *(const short8*)(embHi + ((size_t)((ch + 1) * 16 + n0) * 256 + o0 * 8));
      p1 = *(const short8*)(embHi + ((size_t)((ch + 1) * 16 + n1) * 256 + o1 * 8));
    }
    // compute chunk ch
    f32x4 acc = {0.f, 0.f, 0.f, 0.f};
    const unsigned short* bbuf = sB + cur * (16 * 264);
    #pragma unroll
    for (int ks = 0; ks < 8; ++ks) {
      short8 bfrag = *(const short8*)(bbuf + lane15 * 264 + ks * 32 + quad * 8);
      acc = __builtin_amdgcn_mfma_f32_16x16x32_bf16(aHi[ks], bfrag, acc, 0, 0, 0);
      acc = __builtin_amdgcn_mfma_f32_16x16x32_bf16(aLo[ks], bfrag, acc, 0, 0, 0);
    }
    const int n = ch * 16 + lane15;
    const float en = sNorm[n];
    #pragma unroll
    for (int r = 0; r < 4; ++r) {
      float s = fmaf(-2.0f, acc[r], en);
      if (s < b1[r])      { b2[r] = b1[r]; i2[r] = i1[r]; b1[r] = s; i1[r] = n; }
      else if (s < b2[r]) { b2[r] = s; i2[r] = n; }
    }
    if (ch < 63) {
      __syncthreads();   // all waves done reading buf being overwritten
      unsigned short* nb = sB + (1 - cur) * (16 * 264);
      *(short8*)(nb + n0 * 264 + o0 * 8) = p0;
      *(short8*)(nb + n1 * 264 + o1 * 8) = p1;
      __syncthreads();   // writes visible
    }
  }

  // ---- butterfly top-2 merge across the 16 lanes sharing each pixel ----
  #pragma unroll
  for (int m = 1; m <= 8; m <<= 1) {
    #pragma unroll
    for (int r = 0; r < 4; ++r) {
      float ob1 = __shfl_xor(b1[r], m), ob2 = __shfl_xor(b2[r], m);
      int oi1 = __shfl_xor(i1[r], m), oi2 = __shfl_xor(i2[r], m);
      bool aF = (b1[r] < ob1) || (b1[r] == ob1 && i1[r] < oi1);
      float w1 = aF ? b1[r] : ob1;  int wi1 = aF ? i1[r] : oi1;
      float lf = aF ? ob1 : b1[r];  int lfi = aF ? oi1 : i1[r];   // losing first
      float ws = aF ? b2[r] : ob2;  int wsi = aF ? i2[r] : oi2;   // winner's second
      bool sF = (ws < lf) || (ws == lf && wsi < lfi);
      b1[r] = w1; i1[r] = wi1;
      b2[r] = sF ? ws : lf; i2[r] = sF ? wsi : lfi;
    }
  }
  // lanes 0,16,32,48 hold merged results for pixels quad*4 + r
  if (lane15 == 0) {
    #pragma unroll
    for (int r = 0; r < 4; ++r) {
      const int pix = pix0 + w * 16 + quad * 4 + r;
      if (b2[r] - b1[r] >= MARGIN_S) {
        selIdx[pix] = i1[r];
        out[OUT_IDX + pix] = (float)i1[r];
      } else {
        int pos = atomicAdd(count, 1);
        worklist[pos] = pix;
      }
    }
  }
}

// ---------------- k_refine: exact numpy-fp32 full re-scan, block/pixel ------
__global__ void k_refine(const float* __restrict__ lat, const float* __restrict__ emb,
                         const float* __restrict__ enormQ,
                         const int* __restrict__ count, const int* __restrict__ worklist,
                         int* __restrict__ selIdx, float* __restrict__ out) {
  __shared__ __align__(16) float xs[256];
  __shared__ float sSx;
  __shared__ float rv[4];
  __shared__ int ri[4];
  const int t = threadIdx.x;
  const int cnt = *count;

  for (int wi = blockIdx.x; wi < cnt; wi += gridDim.x) {
    const int pix = worklist[wi];
    const int b = pix >> 10, hw = pix & 1023;
    const float* latB = lat + (size_t)b * BSTRIDE + hw;
    xs[t] = latB[(size_t)t * 1024];
    __syncthreads();

    if (t == 0) {   // numpy-pairwise Sx (validated pattern)
      float blk[2];
      #pragma unroll
      for (int h = 0; h < 2; ++h) {
        const float* a = xs + h * 128;
        float r[8];
        #pragma unroll
        for (int j = 0; j < 8; ++j) r[j] = __fmul_rn(a[j], a[j]);
        for (int i = 8; i < 128; i += 8)
          #pragma unroll
          for (int j = 0; j < 8; ++j) r[j] = __fadd_rn(r[j], __fmul_rn(a[i+j], a[i+j]));
        blk[h] = __fadd_rn(__fadd_rn(__fadd_rn(r[0], r[1]), __fadd_rn(r[2], r[3])),
                           __fadd_rn(__fadd_rn(r[4], r[5]), __fadd_rn(r[6], r[7])));
      }
      sSx = __fadd_rn(blk[0], blk[1]);
    }

    // thread t: codes t*4 .. t*4+3, exact ascending-c fp32 FMA chains
    const float* e0 = emb + (size_t)(t * 4 + 0) * DIM;
    const float* e1 = emb + (size_t)(t * 4 + 1) * DIM;
    const float* e2 = emb + (size_t)(t * 4 + 2) * DIM;
    const float* e3 = emb + (size_t)(t * 4 + 3) * DIM;
    float d0 = 0.f, d1 = 0.f, d2 = 0.f, d3 = 0.f;
    for (int cb = 0; cb < 64; ++cb) {
      float4 xv = *(const float4*)(xs + cb * 4);
      float4 q0 = *(const float4*)(e0 + cb * 4);
      float4 q1 = *(const float4*)(e1 + cb * 4);
      float4 q2 = *(const float4*)(e2 + cb * 4);
      float4 q3 = *(const float4*)(e3 + cb * 4);
      d0 = fmaf(xv.x, q0.x, d0); d0 = fmaf(xv.y, q0.y, d0);
      d0 = fmaf(xv.z, q0.z, d0); d0 = fmaf(xv.w, q0.w, d0);
      d1 = fmaf(xv.x, q1.x, d1); d1 = fmaf(xv.y, q1.y, d1);
      d1 = fmaf(xv.z, q1.z, d1); d1 = fmaf(xv.w, q1.w, d1);
      d2 = fmaf(xv.x, q2.x, d2); d2 = fmaf(xv.y, q2.y, d2);
      d2 = fmaf(xv.z, q2.z, d2); d2 = fmaf(xv.w, q2.w, d2);
      d3 = fmaf(xv.x, q3.x, d3); d3 = fmaf(xv.y, q3.y, d3);
      d3 = fmaf(xv.z, q3.z, d3); d3 = fmaf(xv.w, q3.w, d3);
    }
    __syncthreads();   // sSx ready; xs stable
    const float Sx = sSx;
    float best = INFINITY; int bi = 0x7fffffff;
    float dd[4] = {d0, d1, d2, d3};
    #pragma unroll
    for (int j = 0; j < 4; ++j) {
      const int k = t * 4 + j;
      float dq = __fsub_rn(__fadd_rn(Sx, enormQ[k]), __fmul_rn(2.0f, dd[j]));
      if (dq < best) { best = dq; bi = k; }   // ascending k: strict < = first index
    }
    // lexicographic wave reduce
    for (int off = 32; off > 0; off >>= 1) {
      float ob = __shfl_down(best, off);
      int oi = __shfl_down(bi, off);
      if (ob < best || (ob == best && oi < bi)) { best = ob; bi = oi; }
    }
    if ((t & 63) == 0) { rv[t >> 6] = best; ri[t >> 6] = bi; }
    __syncthreads();
    if (t == 0) {
      float B = rv[0]; int I = ri[0];
      #pragma unroll
      for (int j = 1; j < 4; ++j)
        if (rv[j] < B || (rv[j] == B && ri[j] < I)) { B = rv[j]; I = ri[j]; }
      selIdx[pix] = I;
      out[OUT_IDX + pix] = (float)I;
    }
    __syncthreads();   // xs/sSx reuse safety for next iteration
  }
}

// ---------------- k_gather: gather + straight-through + loss ----------------
__global__ void k_gather(const float* __restrict__ lat, const float* __restrict__ emb,
                         const int* __restrict__ selIdx,
                         float* __restrict__ out, double* __restrict__ lossAcc) {
  __shared__ int sIdx[64];
  const int t = threadIdx.x;
  const int pix0 = blockIdx.x * 64;
  const int b = pix0 >> 10;
  const int hw0 = pix0 & 1023;
  const float* latBase = lat + (size_t)b * BSTRIDE + hw0;

  if (t < 64) sIdx[t] = selIdx[pix0 + t];
  __syncthreads();

  const int cSub = t >> 4;
  const int p4 = (t & 15) * 4;
  const int k0 = sIdx[p4], k1 = sIdx[p4+1], k2 = sIdx[p4+2], k3 = sIdx[p4+3];
  double lsum = 0.0;
  #pragma unroll 4
  for (int i = 0; i < 16; ++i) {
    int c = i * 16 + cSub;
    float4 l = *(const float4*)(latBase + (size_t)c * 1024 + p4);
    float q0 = emb[k0 * DIM + c], q1 = emb[k1 * DIM + c],
          q2 = emb[k2 * DIM + c], q3 = emb[k3 * DIM + c];
    float d0 = q0 - l.x, d1 = q1 - l.y, d2 = q2 - l.z, d3 = q3 - l.w;
    float4 o; o.x = l.x + d0; o.y = l.y + d1; o.z = l.z + d2; o.w = l.w + d3;
    *(float4*)(out + (size_t)b * BSTRIDE + (size_t)c * 1024 + hw0 + p4) = o;
    lsum += (double)d0*d0 + (double)d1*d1 + (double)d2*d2 + (double)d3*d3;
  }
  for (int off = 32; off > 0; off >>= 1) lsum += __shfl_down(lsum, off);
  if ((t & 63) == 0) atomicAdd(lossAcc, lsum);
}

__global__ void k_loss(const double* __restrict__ lossAcc, float* __restrict__ out) {
  double m = *lossAcc * (1.0 / 16777216.0);
  out[OUT_LOSS] = (float)(1.25 * m);
}

extern "C" void kernel_launch(void* const* d_in, const int* in_sizes, int n_in,
                              void* d_out, int out_size, void* d_ws, size_t ws_size,
                              hipStream_t stream) {
  const float* lat = (const float*)d_in[0];
  const float* emb = (const float*)d_in[1];
  float* out = (float*)d_out;
  char* ws = (char*)d_ws;
  double* lossAcc = (double*)(ws + WS_LOSS);
  int* count = (int*)(ws + WS_COUNT);
  float* enormQ = (float*)(ws + WS_ENORM);
  unsigned short* embHi = (unsigned short*)(ws + WS_EMBH);
  int* selIdx = (int*)(ws + WS_SEL);
  int* worklist = (int*)(ws + WS_WL);

  k_prep<<<dim3(16), dim3(64), 0, stream>>>(emb, enormQ, lossAcc, count);
  k_embconv<<<dim3(256), dim3(256), 0, stream>>>(emb, embHi);
  k_score<<<dim3(1024), dim3(256), 0, stream>>>(lat, embHi, enormQ, selIdx, out, count, worklist);
  k_refine<<<dim3(1024), dim3(256), 0, stream>>>(lat, emb, enormQ, count, worklist, selIdx, out);
  k_gather<<<dim3(1024), dim3(256), 0, stream>>>(lat, emb, selIdx, out, lossAcc);
  k_loss<<<dim3(1), dim3(1), 0, stream>>>(lossAcc, out);
}

// Round 7
// 392.964 us; speedup vs baseline: 2.1213x; 2.1213x over previous
//
#include <hip/hip_runtime.h>
#include <math.h>

// VectorQuantizer on MI355X — round 7: refine v3 fix (full-row tile staging).
// latents [64,256,32,32] f32, embedding [1024,256] f32.
// Outputs (concat fp32): quant_st [16777216], loss [1], indices-as-float [65536].
//
// VALIDATED (rounds 2/3/5, absmax 0): numpy index semantics are
//   dist = fl32( fl32(Sx + Ek) - fl32(2*dot) ), argmin first-index ties,
// Sx/Ek = numpy pairwise fp32 (two 128-blocks, 8 accumulators, binary tree),
// dot = sequential ascending-c fp32 FMA chain. MFMA top-2 + margin 3e-4 filter
// + exact re-scan of flagged pixels reproduces it bit-exactly.
//
// ROUND-6 BUG: sE staging loop ran 4 iterations (32 of 64 float4 chunks/row)
// -> columns 128..255 of every tile were uninitialized LDS -> refined pixels
// got garbage argmin. Fixed: 8 iterations.
//
// Pipeline:
//  k_prep    : Ek[k]; zero loss + worklist count
//  k_embconv : emb_hi = bf16(emb)
//  k_score   : MFMA bf16-split engine, per-pixel top-2, margin filter
//  k_refine  : 8 pixels/block-group; 32-code LDS tiles; exact fp32 chains
//  k_gather  : gather + straight-through write + fp64 loss partials
//  k_loss    : loss = 1.25 * total / 16777216

#define DIM 256
#define BSTRIDE 262144
#define OUT_LOSS 16777216
#define OUT_IDX  16777217
#define MARGIN_S 3e-4f

#define RG 8          // refine: pixels per group
#define RTILE 32      // refine: codes per LDS tile
#define RSTRIDE 260   // refine: padded row stride (floats); 260%32=4 -> 4-way max

// ws byte offsets (total 1056768 B)
#define WS_LOSS  0
#define WS_COUNT 8
#define WS_ENORM 64
#define WS_EMBH  8192
#define WS_SEL   532480      // 8192 + 1024*256*2
#define WS_WL    794624      // 532480 + 65536*4

typedef __attribute__((ext_vector_type(8))) short short8;
typedef __attribute__((ext_vector_type(4))) float f32x4;

__device__ inline unsigned short f2bf(float f) {   // RNE f32 -> bf16 bits
  unsigned u = __float_as_uint(f);
  unsigned r = 0x7FFFu + ((u >> 16) & 1u);
  return (unsigned short)((u + r) >> 16);
}
__device__ inline float bf2f(unsigned short h) {
  return __uint_as_float(((unsigned)h) << 16);
}

// ---------------- k_prep: numpy-pairwise |e_k|^2, zero loss/count -----------
__global__ void k_prep(const float* __restrict__ emb, float* __restrict__ enormQ,
                       double* __restrict__ lossAcc, int* __restrict__ count) {
  const int k = blockIdx.x * 64 + threadIdx.x;   // 16 blocks x 64
  if (blockIdx.x == 0 && threadIdx.x == 0) { *lossAcc = 0.0; *count = 0; }
  if (k >= 1024) return;
  const float* e = emb + (size_t)k * DIM;
  float blk[2];
  #pragma unroll
  for (int h = 0; h < 2; ++h) {
    const float* a = e + h * 128;
    float r[8];
    #pragma unroll
    for (int j = 0; j < 8; ++j) r[j] = __fmul_rn(a[j], a[j]);
    for (int i = 8; i < 128; i += 8)
      #pragma unroll
      for (int j = 0; j < 8; ++j) r[j] = __fadd_rn(r[j], __fmul_rn(a[i+j], a[i+j]));
    blk[h] = __fadd_rn(__fadd_rn(__fadd_rn(r[0], r[1]), __fadd_rn(r[2], r[3])),
                       __fadd_rn(__fadd_rn(r[4], r[5]), __fadd_rn(r[6], r[7])));
  }
  enormQ[k] = __fadd_rn(blk[0], blk[1]);
}

// ---------------- k_embconv: emb -> bf16 hi ---------------------------------
__global__ void k_embconv(const float* __restrict__ emb, unsigned short* __restrict__ embHi) {
  const int i = (blockIdx.x * 256 + threadIdx.x) * 4;   // 256 blocks x 256
  float4 v = *(const float4*)(emb + i);
  unsigned r0 = (unsigned)f2bf(v.x) | ((unsigned)f2bf(v.y) << 16);
  unsigned r1 = (unsigned)f2bf(v.z) | ((unsigned)f2bf(v.w) << 16);
  uint2 st; st.x = r0; st.y = r1;
  *(uint2*)(embHi + i) = st;
}

// ---------------- k_score: MFMA engine + top-2 filter -----------------------
// 1024 blocks x 256 threads (4 waves). Block = 64 pixels; wave = 16 pixels.
// A (16 pix x 256 feats, hi+lo bf16) register-resident. B (16 codes) dbuf LDS.
// MFMA 16x16x32: A[m=lane&15][k=quad*8+j], B[n=lane&15][k=quad*8+j],
//                D[m=quad*4+reg][n=lane&15].
__launch_bounds__(256, 2)
__global__ void k_score(const float* __restrict__ lat,
                        const unsigned short* __restrict__ embHi,
                        const float* __restrict__ enormQ,
                        int* __restrict__ selIdx, float* __restrict__ out,
                        int* __restrict__ count, int* __restrict__ worklist) {
  __shared__ __align__(16) unsigned short sB[2 * 16 * 264];  // 16.5 KB (+8/row pad)
  __shared__ float sNorm[1024];                              // 4 KB

  const int t = threadIdx.x;
  const int w = t >> 6;          // wave 0..3
  const int L = t & 63;          // lane
  const int lane15 = L & 15;
  const int quad = L >> 4;

  const int pix0 = blockIdx.x * 64;
  const int bImg = pix0 >> 10;
  const int hw0 = pix0 & 1023;

  for (int i = t; i < 1024; i += 256) sNorm[i] = enormQ[i];

  // ---- A fragments: 16 pixels of this wave, all 8 k-steps, hi+lo ----
  const int myPixHw = hw0 + w * 16 + lane15;
  const float* latPix = lat + (size_t)bImg * BSTRIDE + myPixHw;
  short8 aHi[8], aLo[8];
  #pragma unroll
  for (int ks = 0; ks < 8; ++ks) {
    #pragma unroll
    for (int j = 0; j < 8; ++j) {
      float f = latPix[(size_t)(ks * 32 + quad * 8 + j) * 1024];
      unsigned short hb = f2bf(f);
      unsigned short lb = f2bf(f - bf2f(hb));
      aHi[ks][j] = (short)hb;
      aLo[ks][j] = (short)lb;
    }
  }

  float b1[4], b2[4];
  int i1[4], i2[4];
  #pragma unroll
  for (int r = 0; r < 4; ++r) { b1[r] = INFINITY; b2[r] = INFINITY; i1[r] = 0x7fffffff; i2[r] = 0x7fffffff; }

  const int s0 = t, s1 = 256 + t;
  const int n0 = s0 >> 5, o0 = s0 & 31;
  const int n1 = s1 >> 5, o1 = s1 & 31;

  {
    short8 p0 = *(const short8*)(embHi + ((size_t)(0 * 16 + n0) * 256 + o0 * 8));
    short8 p1 = *(const short8*)(embHi + ((size_t)(0 * 16 + n1) * 256 + o1 * 8));
    *(short8*)(sB + n0 * 264 + o0 * 8) = p0;
    *(short8*)(sB + n1 * 264 + o1 * 8) = p1;
  }
  __syncthreads();

  for (int ch = 0; ch < 64; ++ch) {
    const int cur = ch & 1;
    short8 p0, p1;
    if (ch < 63) {
      p0 = *(const short8*)(embHi + ((size_t)((ch + 1) * 16 + n0) * 256 + o0 * 8));
      p1 = *(const short8*)(embHi + ((size_t)((ch + 1) * 16 + n1) * 256 + o1 * 8));
    }
    f32x4 acc = {0.f, 0.f, 0.f, 0.f};
    const unsigned short* bbuf = sB + cur * (16 * 264);
    #pragma unroll
    for (int ks = 0; ks < 8; ++ks) {
      short8 bfrag = *(const short8*)(bbuf + lane15 * 264 + ks * 32 + quad * 8);
      acc = __builtin_amdgcn_mfma_f32_16x16x32_bf16(aHi[ks], bfrag, acc, 0, 0, 0);
      acc = __builtin_amdgcn_mfma_f32_16x16x32_bf16(aLo[ks], bfrag, acc, 0, 0, 0);
    }
    const int n = ch * 16 + lane15;
    const float en = sNorm[n];
    #pragma unroll
    for (int r = 0; r < 4; ++r) {
      float s = fmaf(-2.0f, acc[r], en);
      if (s < b1[r])      { b2[r] = b1[r]; i2[r] = i1[r]; b1[r] = s; i1[r] = n; }
      else if (s < b2[r]) { b2[r] = s; i2[r] = n; }
    }
    if (ch < 63) {
      __syncthreads();
      unsigned short* nb = sB + (1 - cur) * (16 * 264);
      *(short8*)(nb + n0 * 264 + o0 * 8) = p0;
      *(short8*)(nb + n1 * 264 + o1 * 8) = p1;
      __syncthreads();
    }
  }

  // butterfly top-2 merge across the 16 lanes sharing each pixel
  #pragma unroll
  for (int m = 1; m <= 8; m <<= 1) {
    #pragma unroll
    for (int r = 0; r < 4; ++r) {
      float ob1 = __shfl_xor(b1[r], m), ob2 = __shfl_xor(b2[r], m);
      int oi1 = __shfl_xor(i1[r], m), oi2 = __shfl_xor(i2[r], m);
      bool aF = (b1[r] < ob1) || (b1[r] == ob1 && i1[r] < oi1);
      float w1 = aF ? b1[r] : ob1;  int wi1 = aF ? i1[r] : oi1;
      float lf = aF ? ob1 : b1[r];  int lfi = aF ? oi1 : i1[r];
      float ws = aF ? b2[r] : ob2;  int wsi = aF ? i2[r] : oi2;
      bool sF = (ws < lf) || (ws == lf && wsi < lfi);
      b1[r] = w1; i1[r] = wi1;
      b2[r] = sF ? ws : lf; i2[r] = sF ? wsi : lfi;
    }
  }
  if (lane15 == 0) {
    #pragma unroll
    for (int r = 0; r < 4; ++r) {
      const int pix = pix0 + w * 16 + quad * 4 + r;
      if (b2[r] - b1[r] >= MARGIN_S) {
        selIdx[pix] = i1[r];
        out[OUT_IDX + pix] = (float)i1[r];
      } else {
        int pos = atomicAdd(count, 1);
        worklist[pos] = pix;
      }
    }
  }
}

// ---------------- k_refine v3: LDS mini-GEMM exact re-scan ------------------
// 1024 blocks x 256 threads. Group = RG(8) pixels; wave w covers pixels
// 2w,2w+1 (one per half-wave); lane&31 owns one code of each RTILE(32) tile.
// Codebook tile staged coalesced into LDS (rows padded to 260 floats).
// Dot = validated sequential ascending-c fp32 FMA chain, operands from LDS.
__launch_bounds__(256, 2)
__global__ void k_refine(const float* __restrict__ lat, const float* __restrict__ emb,
                         const float* __restrict__ enormQ,
                         const int* __restrict__ count, const int* __restrict__ worklist,
                         int* __restrict__ selIdx, float* __restrict__ out) {
  __shared__ __align__(16) float sE[RTILE * RSTRIDE];   // 33,280 B
  __shared__ __align__(16) float sX[RG * RSTRIDE];      // 8,320 B
  __shared__ float sSx[RG];
  const int t = threadIdx.x;
  const int cnt = *count;
  if (cnt == 0) return;
  const int ngroups = (cnt + RG - 1) / RG;
  const int w = t >> 6, lane = t & 63;
  const int sub = lane >> 5;           // half-wave: 0 or 1
  const int kLane = lane & 31;         // code slot within tile
  const int pixSlot = w * 2 + sub;     // 0..7

  for (int g = blockIdx.x; g < ngroups; g += gridDim.x) {
    // ---- stage RG pixels' latents (tail pixels clamped, never written) ----
    {
      const int p = t >> 5, c0 = t & 31;    // 32 threads per pixel
      int wi = g * RG + p; if (wi >= cnt) wi = cnt - 1;
      const int pix = worklist[wi];
      const float* latB = lat + (size_t)(pix >> 10) * BSTRIDE + (pix & 1023);
      #pragma unroll
      for (int i = 0; i < 8; ++i) {
        int c = c0 + 32 * i;
        sX[p * RSTRIDE + c] = latB[(size_t)c * 1024];
      }
    }
    __syncthreads();
    // ---- per-pixel numpy-pairwise Sx (threads 0..RG-1) ----
    if (t < RG) {
      const float* a0 = sX + t * RSTRIDE;
      float blk[2];
      #pragma unroll
      for (int h = 0; h < 2; ++h) {
        const float* a = a0 + h * 128;
        float r[8];
        #pragma unroll
        for (int j = 0; j < 8; ++j) r[j] = __fmul_rn(a[j], a[j]);
        for (int i = 8; i < 128; i += 8)
          #pragma unroll
          for (int j = 0; j < 8; ++j) r[j] = __fadd_rn(r[j], __fmul_rn(a[i+j], a[i+j]));
        blk[h] = __fadd_rn(__fadd_rn(__fadd_rn(r[0], r[1]), __fadd_rn(r[2], r[3])),
                           __fadd_rn(__fadd_rn(r[4], r[5]), __fadd_rn(r[6], r[7])));
      }
      sSx[t] = __fadd_rn(blk[0], blk[1]);
    }

    float best = INFINITY; int bi = 0x7fffffff;
    const float* xrow = sX + pixSlot * RSTRIDE;
    for (int tile = 0; tile < 32; ++tile) {
      __syncthreads();   // prev-tile reads done (also orders sSx writes)
      // stage tile: 32 rows x 256 floats (64 float4/row; 8 threads/row x 8)
      {
        const int r = t >> 3, q0 = t & 7;   // 8 threads per row
        const float* src = emb + (size_t)(tile * RTILE + r) * 256;
        #pragma unroll
        for (int i = 0; i < 8; ++i) {       // ROUND-6 BUG: was i < 4 (half row)
          int q = q0 + 8 * i;
          *(float4*)(sE + r * RSTRIDE + q * 4) = *(const float4*)(src + q * 4);
        }
      }
      __syncthreads();
      // exact ascending-c chain from LDS
      const float* erow = sE + kLane * RSTRIDE;
      float d = 0.f;
      for (int c = 0; c < 256; c += 4) {
        float4 xv = *(const float4*)(xrow + c);
        float4 ev = *(const float4*)(erow + c);
        d = fmaf(xv.x, ev.x, d); d = fmaf(xv.y, ev.y, d);
        d = fmaf(xv.z, ev.z, d); d = fmaf(xv.w, ev.w, d);
      }
      const int k = tile * RTILE + kLane;
      float dq = __fsub_rn(__fadd_rn(sSx[pixSlot], enormQ[k]), __fmul_rn(2.0f, d));
      if (dq < best) { best = dq; bi = k; }   // ascending k per lane
    }
    // lexicographic reduce within each half-wave (pre-update read semantics
    // keep the tree correct; polluted upper lanes are never re-consumed)
    for (int off = 16; off > 0; off >>= 1) {
      float ob = __shfl_down(best, off);
      int oi = __shfl_down(bi, off);
      if (ob < best || (ob == best && oi < bi)) { best = ob; bi = oi; }
    }
    if (kLane == 0) {
      const int wi = g * RG + pixSlot;
      if (wi < cnt) {
        const int pix = worklist[wi];
        selIdx[pix] = bi;
        out[OUT_IDX + pix] = (float)bi;
      }
    }
    __syncthreads();   // sX/sSx stable until all waves finish the group
  }
}

// ---------------- k_gather: gather + straight-through + loss ----------------
__global__ void k_gather(const float* __restrict__ lat, const float* __restrict__ emb,
                         const int* __restrict__ selIdx,
                         float* __restrict__ out, double* __restrict__ lossAcc) {
  __shared__ int sIdx[64];
  const int t = threadIdx.x;
  const int pix0 = blockIdx.x * 64;
  const int b = pix0 >> 10;
  const int hw0 = pix0 & 1023;
  const float* latBase = lat + (size_t)b * BSTRIDE + hw0;

  if (t < 64) sIdx[t] = selIdx[pix0 + t];
  __syncthreads();

  const int cSub = t >> 4;
  const int p4 = (t & 15) * 4;
  const int k0 = sIdx[p4], k1 = sIdx[p4+1], k2 = sIdx[p4+2], k3 = sIdx[p4+3];
  double lsum = 0.0;
  #pragma unroll 4
  for (int i = 0; i < 16; ++i) {
    int c = i * 16 + cSub;
    float4 l = *(const float4*)(latBase + (size_t)c * 1024 + p4);
    float q0 = emb[k0 * DIM + c], q1 = emb[k1 * DIM + c],
          q2 = emb[k2 * DIM + c], q3 = emb[k3 * DIM + c];
    float d0 = q0 - l.x, d1 = q1 - l.y, d2 = q2 - l.z, d3 = q3 - l.w;
    float4 o; o.x = l.x + d0; o.y = l.y + d1; o.z = l.z + d2; o.w = l.w + d3;
    *(float4*)(out + (size_t)b * BSTRIDE + (size_t)c * 1024 + hw0 + p4) = o;
    lsum += (double)d0*d0 + (double)d1*d1 + (double)d2*d2 + (double)d3*d3;
  }
  for (int off = 32; off > 0; off >>= 1) lsum += __shfl_down(lsum, off);
  if ((t & 63) == 0) atomicAdd(lossAcc, lsum);
}

__global__ void k_loss(const double* __restrict__ lossAcc, float* __restrict__ out) {
  double m = *lossAcc * (1.0 / 16777216.0);
  out[OUT_LOSS] = (float)(1.25 * m);
}

extern "C" void kernel_launch(void* const* d_in, const int* in_sizes, int n_in,
                              void* d_out, int out_size, void* d_ws, size_t ws_size,
                              hipStream_t stream) {
  const float* lat = (const float*)d_in[0];
  const float* emb = (const float*)d_in[1];
  float* out = (float*)d_out;
  char* ws = (char*)d_ws;
  double* lossAcc = (double*)(ws + WS_LOSS);
  int* count = (int*)(ws + WS_COUNT);
  float* enormQ = (float*)(ws + WS_ENORM);
  unsigned short* embHi = (unsigned short*)(ws + WS_EMBH);
  int* selIdx = (int*)(ws + WS_SEL);
  int* worklist = (int*)(ws + WS_WL);

  k_prep<<<dim3(16), dim3(64), 0, stream>>>(emb, enormQ, lossAcc, count);
  k_embconv<<<dim3(256), dim3(256), 0, stream>>>(emb, embHi);
  k_score<<<dim3(1024), dim3(256), 0, stream>>>(lat, embHi, enormQ, selIdx, out, count, worklist);
  k_refine<<<dim3(1024), dim3(256), 0, stream>>>(lat, emb, enormQ, count, worklist, selIdx, out);
  k_gather<<<dim3(1024), dim3(256), 0, stream>>>(lat, emb, selIdx, out, lossAcc);
  k_loss<<<dim3(1), dim3(1), 0, stream>>>(lossAcc, out);
}